// Round 12
// baseline (662.778 us; speedup 1.0000x reference)
//
#include <hip/hip_runtime.h>
#include <math.h>

#define D_DIM 2048
#define T_N   245
#define TOPK  8
#define BM    64
#define NCH   32              // 2048 / 64

typedef __attribute__((ext_vector_type(8))) __bf16 bf16x8;
typedef __attribute__((ext_vector_type(4))) float  f32x4;

// ws layout (~2.4 MB):
//   [0]        : unsigned counter
//   [256]      : token list, unsigned[32768] (128 KB)
//   [256K]     : wtp packed fragments, bf16 [32][16][2][2][64][8]  (2 MB)
#define WS_LIST_OFF   256
#define WS_WTP_OFF    (256 * 1024)

// packed strides (bf16 units)
#define P_C    32768          // 16*2*2*64*8
#define P_FCG  2048           // 2*2*64*8
#define P_KS   1024           // 2*64*8
#define P_HL   512            // 64*8

__device__ __forceinline__ unsigned short bf16_rne(float f) {
    unsigned u = __builtin_bit_cast(unsigned, f);
    u += 0x7FFFu + ((u >> 16) & 1u);
    return (unsigned short)(u >> 16);
}
__device__ __forceinline__ float bf16_to_f(unsigned short h) {
    return __builtin_bit_cast(float, (unsigned)h << 16);
}

// async global->LDS, 16 B per lane: one instr stages 4 rows (1 KB)
__device__ __forceinline__ void gll16(const float* g, float* l) {
    __builtin_amdgcn_global_load_lds(
        (const __attribute__((address_space(1))) void*)g,
        (__attribute__((address_space(3))) void*)l, 16, 0, 0);
}

// split 8 f32 -> hi/lo bf16x8 using v_cvt_pk_bf16_f32 (RNE)
__device__ __forceinline__ void split8(const float4& A, const float4& B,
                                       bf16x8& h8, bf16x8& l8) {
    const float f[8] = {A.x, A.y, A.z, A.w, B.x, B.y, B.z, B.w};
    unsigned hu[4], lu[4];
#pragma unroll
    for (int p = 0; p < 4; ++p) {
        unsigned uh;
        asm("v_cvt_pk_bf16_f32 %0, %1, %2" : "=v"(uh) : "v"(f[2*p]), "v"(f[2*p+1]));
        const float h0 = __builtin_bit_cast(float, uh << 16);
        const float h1 = __builtin_bit_cast(float, uh & 0xffff0000u);
        const float l0 = f[2*p] - h0;
        const float l1 = f[2*p+1] - h1;
        unsigned ul;
        asm("v_cvt_pk_bf16_f32 %0, %1, %2" : "=v"(ul) : "v"(l0), "v"(l1));
        hu[p] = uh; lu[p] = ul;
    }
    uint4 vh = make_uint4(hu[0], hu[1], hu[2], hu[3]);
    uint4 vl = make_uint4(lu[0], lu[1], lu[2], lu[3]);
    h8 = __builtin_bit_cast(bf16x8, vh);
    l8 = __builtin_bit_cast(bf16x8, vl);
}

// ---------------------------------------------------------------------------
// Prep: W [2048][245] fp32 -> wtp packed fragment-major bf16 hi/lo.
// ---------------------------------------------------------------------------
__global__ __launch_bounds__(256)
void prep_pack(const float* __restrict__ W,
               unsigned* __restrict__ cnt,
               unsigned short* __restrict__ wtp)
{
    if (blockIdx.x == 0 && blockIdx.y == 0 && threadIdx.x == 0) *cnt = 0u;

    const int c   = blockIdx.x;          // 0..31
    const int fcg = blockIdx.y;          // 0..15
    const int tid = threadIdx.x;
    const int ks   = tid >> 7;           // 0..1
    const int hl   = (tid >> 6) & 1;     // 0..1
    const int lane = tid & 63;

    const int row = fcg * 16 + (lane & 15);
    const int kb  = c * 64 + ks * 32 + (lane >> 4) * 8;

    unsigned short v[8];
#pragma unroll
    for (int j = 0; j < 8; ++j) {
        const float f = (row < T_N) ? W[(long)(kb + j) * T_N + row] : 0.0f;
        const unsigned short h = bf16_rne(f);
        v[j] = hl ? bf16_rne(f - bf16_to_f(h)) : h;
    }
    const long off = (long)c * P_C + (long)fcg * P_FCG + ks * P_KS
                     + hl * P_HL + lane * 8;
    *reinterpret_cast<uint4*>(wtp + off) = *reinterpret_cast<const uint4*>(v);
}

// ---------------------------------------------------------------------------
// Main router (round-11 structure + cross-chunk B-hi register prefetch with
// counted-vmcnt raw barrier):
//   bh(c+1) issued during chunk c (full-chunk latency cover); bl(c) loaded
//   in-chunk (pass-3 use). End-of-chunk: s_waitcnt vmcnt(10) (= bhN 8 +
//   stores 2 younger than the glls; order pinned by sched_barrier(0)) +
//   raw s_barrier -> prefetch and stores never drain to 0.
// ---------------------------------------------------------------------------
__global__ __launch_bounds__(512, 4)
void router_mfma(const float* __restrict__ x,
                 const unsigned short* __restrict__ wtp,
                 const float* __restrict__ br,
                 const int*   __restrict__ conn,
                 float* __restrict__ out_x,
                 float* __restrict__ out_p,
                 float* __restrict__ out_n,
                 unsigned* __restrict__ cnt,
                 unsigned* __restrict__ list)
{
    __shared__ float smem[8320];         // xbuf[2][64][64] (32KB) | slog[32][260]

    const int tid  = threadIdx.x;
    const int lane = tid & 63;
    const int wid  = tid >> 6;           // 0..7
    const int wr   = wid >> 2;           // 0..1 (row half)
    const int wc   = wid & 3;            // 0..3 (col quarter)
    const int m16  = lane & 15;
    const int kq   = lane >> 4;          // 0..3
    const long row0 = (long)blockIdx.x * BM;

    f32x4 acc[2][4];
#pragma unroll
    for (int fr = 0; fr < 2; ++fr)
#pragma unroll
        for (int fc = 0; fc < 4; ++fc)
            acc[fr][fc] = (f32x4){0.f, 0.f, 0.f, 0.f};

    // stage chunk c: 2 gll16 per wave; each instr covers 4 rows (1 KB).
    auto stage = [&](int c, int bufW) {
#pragma unroll
        for (int q = 0; q < 2; ++q) {
            const int rbase = wid * 8 + q * 4;
            const int r     = rbase + (lane >> 4);
            const int u     = (lane & 15) ^ (r & 15);
            gll16(x + (row0 + r) * (long)D_DIM + c * 64 + u * 4,
                  &smem[bufW + rbase * 64]);
        }
    };
    // load one hi/lo half of chunk c's packed B fragments (8 uint4)
    auto loadB = [&](int c, int hl, uint4 (&dst)[4][2]) {
        const unsigned short* pc = wtp + (long)c * P_C + (long)wc * 4 * P_FCG
                                   + hl * P_HL + lane * 8;
#pragma unroll
        for (int fc = 0; fc < 4; ++fc)
#pragma unroll
            for (int ks = 0; ks < 2; ++ks)
                dst[fc][ks] = *reinterpret_cast<const uint4*>(
                    pc + fc * P_FCG + ks * P_KS);
    };

    uint4 bhA[4][2], bhB[4][2];

    // ---- prologue: stage(0) + bh(0), full drain once ----
    stage(0, 0);
    loadB(0, 0, bhA);
    __syncthreads();

    // chunk body; BP = bh(c) resident, BN <- bh(c+1) prefetch
    auto body = [&](int c, uint4 (&BP)[4][2], uint4 (&BN)[4][2]) {
        const int k0   = c * 64;
        const int bufW = (c & 1) * 4096;

        // ---- bl(c) (in-chunk; used only in pass 3) ----
        uint4 bl[4][2];
        loadB(c, 1, bl);

        // ---- gll(c+1); nothing below may hoist above it ----
        if (c + 1 < NCH) stage(c + 1, ((c + 1) & 1) * 4096);
        __builtin_amdgcn_sched_barrier(0);

        // ---- bh(c+1) prefetch (consumed after next barrier) ----
        if (c + 1 < NCH) loadB(c + 1, 0, BN);

        // ---- x passthrough: full-line non-temporal stores from LDS ----
        {
            const int row = tid >> 4;        // 0..31
            const int u   = tid & 15;
#pragma unroll
            for (int rg = 0; rg < 2; ++rg) {
                const int r = rg * 32 + row;
                f32x4 v = *reinterpret_cast<const f32x4*>(
                    &smem[bufW + r * 64 + (u ^ (r & 15)) * 4]);
                __builtin_nontemporal_store(v, reinterpret_cast<f32x4*>(
                    out_x + (row0 + r) * (long)D_DIM + k0 + u * 4));
            }
        }

        // ---- compute: 2 k-steps x 3 passes (hi*hi, lo*hi, hi*lo) ----
#pragma unroll
        for (int ks = 0; ks < 2; ++ks) {
            bf16x8 ah[2], al[2];
#pragma unroll
            for (int fr = 0; fr < 2; ++fr) {
                const int row = wr * 32 + fr * 16 + m16;   // row & 15 == m16
                const int u0  = ks * 8 + kq * 2;
                float4 r0 = *reinterpret_cast<const float4*>(
                    &smem[bufW + row * 64 + ((u0)     ^ m16) * 4]);
                float4 r1 = *reinterpret_cast<const float4*>(
                    &smem[bufW + row * 64 + ((u0 + 1) ^ m16) * 4]);
                split8(r0, r1, ah[fr], al[fr]);
            }
            __builtin_amdgcn_s_setprio(1);
#pragma unroll
            for (int fc = 0; fc < 4; ++fc) {
                const bf16x8 bhv = __builtin_bit_cast(bf16x8, BP[fc][ks]);
                const bf16x8 blv = __builtin_bit_cast(bf16x8, bl[fc][ks]);
#pragma unroll
                for (int fr = 0; fr < 2; ++fr) {
                    acc[fr][fc] = __builtin_amdgcn_mfma_f32_16x16x32_bf16(ah[fr], bhv, acc[fr][fc], 0, 0, 0);
                    acc[fr][fc] = __builtin_amdgcn_mfma_f32_16x16x32_bf16(al[fr], bhv, acc[fr][fc], 0, 0, 0);
                    acc[fr][fc] = __builtin_amdgcn_mfma_f32_16x16x32_bf16(ah[fr], blv, acc[fr][fc], 0, 0, 0);
                }
            }
            __builtin_amdgcn_s_setprio(0);
        }

        // ---- counted-vmcnt raw barrier: glls(c+1) done; bhN + stores stay
        // in flight (10 = 8 bhN + 2 stores younger than the glls) ----
        if (c + 1 < NCH) {
            __builtin_amdgcn_sched_barrier(0);
            asm volatile("s_waitcnt vmcnt(10)" ::: "memory");
            __builtin_amdgcn_s_barrier();
            __builtin_amdgcn_sched_barrier(0);
        }
    };

    for (int c = 0; c < NCH; c += 2) {   // static parity (rule #20)
        body(c,     bhA, bhB);
        body(c + 1, bhB, bhA);
    }

    // ---- epilogue: two 32-row halves; register-resident softmax/top-8 ----
#pragma unroll 1
    for (int h = 0; h < 2; ++h) {
        __syncthreads();
        if (wr == h) {
#pragma unroll
            for (int fr = 0; fr < 2; ++fr)
#pragma unroll
                for (int fc = 0; fc < 4; ++fc)
#pragma unroll
                    for (int r = 0; r < 4; ++r) {
                        const int rloc = fr * 16 + kq * 4 + r;     // 0..31
                        const int col  = wc * 64 + fc * 16 + m16;
                        float v = acc[fr][fc][r];
                        v = (col < T_N) ? v + br[col] : -1e30f;
                        smem[rloc * 260 + col] = v;
                    }
        }
        __syncthreads();

        const int rloc = tid >> 4;          // 0..31
        const int sub  = tid & 15;          // 16 threads per row
        const long gr  = row0 + h * 32 + rloc;
        const float* base = &smem[rloc * 260];

        float vals[16];
#pragma unroll
        for (int t = 0; t < 16; ++t) vals[t] = base[sub + 16 * t];

        float m = -INFINITY;
#pragma unroll
        for (int t = 0; t < 16; ++t) m = fmaxf(m, vals[t]);
#pragma unroll
        for (int d = 8; d >= 1; d >>= 1) m = fmaxf(m, __shfl_xor(m, d, 16));

        float e[16]; float s = 0.f;
#pragma unroll
        for (int t = 0; t < 16; ++t) { e[t] = expf(vals[t] - m); s += e[t]; }
#pragma unroll
        for (int d = 8; d >= 1; d >>= 1) s += __shfl_xor(s, d, 16);
        const float inv = 1.0f / s;

        unsigned chosen = 0u;
        float prev = INFINITY;
        int flag = 0;
#pragma unroll 1
        for (int k = 0; k < TOPK + 1; ++k) {
            float bv = -1.f; int bt = 0;
#pragma unroll
            for (int t = 0; t < 16; ++t)
                if (!((chosen >> t) & 1u) && e[t] > bv) { bv = e[t]; bt = t; }
            int bcol = sub + 16 * bt;
#pragma unroll
            for (int d = 8; d >= 1; d >>= 1) {
                const float ov = __shfl_xor(bv, d, 16);
                const int   oc = __shfl_xor(bcol, d, 16);
                if (ov > bv || (ov == bv && oc < bcol)) { bv = ov; bcol = oc; }
            }
            if (bv >= prev * 0.9998f) flag = 1;     // logit gap < 2e-4
            prev = bv;
            if (k < TOPK) {
                if ((bcol & 15) == sub) chosen |= 1u << (bcol >> 4);
                if (sub == 0) {
                    out_p[gr * TOPK + k] = bv * inv;
                    const int* cp = conn + bcol * 3;
                    out_n[(gr * TOPK + k) * 3 + 0] = (float)cp[0];
                    out_n[(gr * TOPK + k) * 3 + 1] = (float)cp[1];
                    out_n[(gr * TOPK + k) * 3 + 2] = (float)cp[2];
                }
            }
        }
        if (sub == 0 && flag) {
            unsigned idx = atomicAdd(cnt, 1u);
            if (idx < 32768u) list[idx] = (unsigned)gr;
        }
    }
}

// ---------------------------------------------------------------------------
// Refine: fp64 recompute for flagged tokens (round-7/8 proven: branchless
// clamped loads, MLP 16, 4 tokens/block, wave-parallel top-8).
// ---------------------------------------------------------------------------
#define RB 4
__global__ __launch_bounds__(512)
void refine_fp64(const float* __restrict__ x,
                 const float* __restrict__ W,
                 const float* __restrict__ br,
                 const int*   __restrict__ conn,
                 float* __restrict__ out_p,
                 float* __restrict__ out_n,
                 const unsigned* __restrict__ cnt,
                 const unsigned* __restrict__ list)
{
    __shared__ float  sx[RB][D_DIM];      // 32 KB
    __shared__ double spart[2][RB][256];  // 16 KB
    __shared__ double slog[RB][256];      // 8 KB

    const int tid  = threadIdx.x;
    const int col  = tid & 255;
    const int kh   = tid >> 8;            // 0..1
    const int colc = (col < T_N) ? col : (T_N - 1);   // branchless clamp
    const int lane = tid & 63;
    const int w    = tid >> 6;            // 0..7
    const unsigned count = min(*cnt, 32768u);

    for (unsigned g0 = (unsigned)blockIdx.x * RB; g0 < count;
         g0 += gridDim.x * RB) {
        const int nb = (int)min((unsigned)RB, count - g0);
        long toks[RB];
#pragma unroll
        for (int j = 0; j < RB; ++j) {
            const unsigned idx = (g0 + j < count) ? (g0 + j) : (count - 1);
            toks[j] = (long)list[idx];
            *reinterpret_cast<float4*>(&sx[j][tid * 4]) =
                *reinterpret_cast<const float4*>(x + toks[j] * D_DIM + tid * 4);
        }
        __syncthreads();

        const int kb = kh * 1024;
        double a0 = 0.0, a1 = 0.0, a2 = 0.0, a3 = 0.0;
        for (int k0 = 0; k0 < 1024; k0 += 16) {
            float wv[16];
#pragma unroll
            for (int i = 0; i < 16; ++i)
                wv[i] = W[(long)(kb + k0 + i) * T_N + colc];  // unconditional
#pragma unroll
            for (int i = 0; i < 16; i += 2) {
                const float2 x0 = *reinterpret_cast<const float2*>(&sx[0][kb + k0 + i]);
                const float2 x1 = *reinterpret_cast<const float2*>(&sx[1][kb + k0 + i]);
                const float2 x2 = *reinterpret_cast<const float2*>(&sx[2][kb + k0 + i]);
                const float2 x3 = *reinterpret_cast<const float2*>(&sx[3][kb + k0 + i]);
                const double w0 = (double)wv[i], w1 = (double)wv[i + 1];
                a0 += (double)x0.x * w0; a0 += (double)x0.y * w1;
                a1 += (double)x1.x * w0; a1 += (double)x1.y * w1;
                a2 += (double)x2.x * w0; a2 += (double)x2.y * w1;
                a3 += (double)x3.x * w0; a3 += (double)x3.y * w1;
            }
        }
        spart[kh][0][col] = a0;
        spart[kh][1][col] = a1;
        spart[kh][2][col] = a2;
        spart[kh][3][col] = a3;
        __syncthreads();

        if (tid < 256) {
#pragma unroll
            for (int j = 0; j < RB; ++j)
                slog[j][tid] = (tid < T_N)
                    ? spart[0][j][tid] + spart[1][j][tid] + (double)br[tid]
                    : -1.0e300;
        }
        __syncthreads();

        if (w < nb) {
            const long tok = toks[w];
            double v[4];
#pragma unroll
            for (int i = 0; i < 4; ++i) v[i] = slog[w][lane + 64 * i];
            double m = fmax(fmax(v[0], v[1]), fmax(v[2], v[3]));
#pragma unroll
            for (int off = 32; off >= 1; off >>= 1)
                m = fmax(m, __shfl_xor(m, off));
            double e[4]; double s = 0.0;
#pragma unroll
            for (int i = 0; i < 4; ++i) {
                e[i] = (v[i] > -1.0e299) ? exp(v[i] - m) : 0.0;
                s += e[i];
            }
#pragma unroll
            for (int off = 32; off >= 1; off >>= 1)
                s += __shfl_xor(s, off);
            const double invZ = 1.0 / s;

            int sel[TOPK];
#pragma unroll 1
            for (int k = 0; k < TOPK; ++k) {
                double bv = -1.0; int bi = 255;
#pragma unroll
                for (int i = 0; i < 4; ++i) {
                    const int t = lane + 64 * i;
                    bool used = false;
                    for (int q = 0; q < k; ++q) used |= (sel[q] == t);
                    if (!used && e[i] > bv) { bv = e[i]; bi = t; }
                }
#pragma unroll
                for (int off = 32; off >= 1; off >>= 1) {
                    const double ov = __shfl_xor(bv, off);
                    const int    oi = __shfl_xor(bi, off);
                    if (ov > bv || (ov == bv && oi < bi)) { bv = ov; bi = oi; }
                }
                sel[k] = bi;
                if (lane == 0) {
                    out_p[tok * TOPK + k] = (float)(bv * invZ);
                    const int* cp = conn + bi * 3;
                    out_n[(tok * TOPK + k) * 3 + 0] = (float)cp[0];
                    out_n[(tok * TOPK + k) * 3 + 1] = (float)cp[1];
                    out_n[(tok * TOPK + k) * 3 + 2] = (float)cp[2];
                }
            }
        }
        __syncthreads();
    }
}

extern "C" void kernel_launch(void* const* d_in, const int* in_sizes, int n_in,
                              void* d_out, int out_size, void* d_ws, size_t ws_size,
                              hipStream_t stream) {
    const float* x    = (const float*)d_in[0];
    const float* Wr   = (const float*)d_in[1];
    const float* br   = (const float*)d_in[2];
    const int*   conn = (const int*)d_in[3];

    float* out_x = (float*)d_out;
    float* out_p = out_x + (size_t)8 * 4096 * 2048;
    float* out_n = out_p + (size_t)8 * 4096 * 8;

    unsigned*       cnt  = (unsigned*)d_ws;
    unsigned*       list = (unsigned*)((char*)d_ws + WS_LIST_OFF);
    unsigned short* wtp  = (unsigned short*)((char*)d_ws + WS_WTP_OFF);

    hipLaunchKernelGGL(prep_pack, dim3(32, 16), dim3(256), 0, stream,
                       Wr, cnt, wtp);
    hipLaunchKernelGGL(router_mfma, dim3(32768 / BM), dim3(512), 0, stream,
                       x, wtp, br, conn, out_x, out_p, out_n, cnt, list);
    hipLaunchKernelGGL(refine_fp64, dim3(512), dim3(512), 0, stream,
                       x, Wr, br, conn, out_p, out_n, cnt, list);
}

// Round 13
// 315.045 us; speedup vs baseline: 2.1038x; 2.1038x over previous
//
#include <hip/hip_runtime.h>
#include <math.h>

#define D_DIM 2048
#define T_N   245
#define TOPK  8
#define BM    64
#define NCH   32              // 2048 / 64

typedef __attribute__((ext_vector_type(8))) __bf16 bf16x8;
typedef __attribute__((ext_vector_type(4))) float  f32x4;

// ws layout (~2.4 MB):
//   [0]        : unsigned counter
//   [256]      : token list, unsigned[32768] (128 KB)
//   [256K]     : wtp packed fragments, bf16 [32][16][2][2][64][8]  (2 MB)
#define WS_LIST_OFF   256
#define WS_WTP_OFF    (256 * 1024)

// packed strides (bf16 units)
#define P_C    32768          // 16*2*2*64*8
#define P_FCG  2048           // 2*2*64*8
#define P_KS   1024           // 2*64*8
#define P_HL   512            // 64*8

__device__ __forceinline__ unsigned short bf16_rne(float f) {
    unsigned u = __builtin_bit_cast(unsigned, f);
    u += 0x7FFFu + ((u >> 16) & 1u);
    return (unsigned short)(u >> 16);
}
__device__ __forceinline__ float bf16_to_f(unsigned short h) {
    return __builtin_bit_cast(float, (unsigned)h << 16);
}

// async global->LDS, 16 B per lane: one instr stages 4 rows (1 KB)
__device__ __forceinline__ void gll16(const float* g, float* l) {
    __builtin_amdgcn_global_load_lds(
        (const __attribute__((address_space(1))) void*)g,
        (__attribute__((address_space(3))) void*)l, 16, 0, 0);
}

// split 8 f32 -> hi/lo bf16x8 using v_cvt_pk_bf16_f32 (RNE)
__device__ __forceinline__ void split8(const float4& A, const float4& B,
                                       bf16x8& h8, bf16x8& l8) {
    const float f[8] = {A.x, A.y, A.z, A.w, B.x, B.y, B.z, B.w};
    unsigned hu[4], lu[4];
#pragma unroll
    for (int p = 0; p < 4; ++p) {
        unsigned uh;
        asm("v_cvt_pk_bf16_f32 %0, %1, %2" : "=v"(uh) : "v"(f[2*p]), "v"(f[2*p+1]));
        const float h0 = __builtin_bit_cast(float, uh << 16);
        const float h1 = __builtin_bit_cast(float, uh & 0xffff0000u);
        const float l0 = f[2*p] - h0;
        const float l1 = f[2*p+1] - h1;
        unsigned ul;
        asm("v_cvt_pk_bf16_f32 %0, %1, %2" : "=v"(ul) : "v"(l0), "v"(l1));
        hu[p] = uh; lu[p] = ul;
    }
    uint4 vh = make_uint4(hu[0], hu[1], hu[2], hu[3]);
    uint4 vl = make_uint4(lu[0], lu[1], lu[2], lu[3]);
    h8 = __builtin_bit_cast(bf16x8, vh);
    l8 = __builtin_bit_cast(bf16x8, vl);
}

// ---------------------------------------------------------------------------
// Prep: W [2048][245] fp32 -> wtp packed fragment-major bf16 hi/lo.
// ---------------------------------------------------------------------------
__global__ __launch_bounds__(256)
void prep_pack(const float* __restrict__ W,
               unsigned* __restrict__ cnt,
               unsigned short* __restrict__ wtp)
{
    if (blockIdx.x == 0 && blockIdx.y == 0 && threadIdx.x == 0) *cnt = 0u;

    const int c   = blockIdx.x;          // 0..31
    const int fcg = blockIdx.y;          // 0..15
    const int tid = threadIdx.x;
    const int ks   = tid >> 7;           // 0..1
    const int hl   = (tid >> 6) & 1;     // 0..1
    const int lane = tid & 63;

    const int row = fcg * 16 + (lane & 15);
    const int kb  = c * 64 + ks * 32 + (lane >> 4) * 8;

    unsigned short v[8];
#pragma unroll
    for (int j = 0; j < 8; ++j) {
        const float f = (row < T_N) ? W[(long)(kb + j) * T_N + row] : 0.0f;
        const unsigned short h = bf16_rne(f);
        v[j] = hl ? bf16_rne(f - bf16_to_f(h)) : h;
    }
    const long off = (long)c * P_C + (long)fcg * P_FCG + ks * P_KS
                     + hl * P_HL + lane * 8;
    *reinterpret_cast<uint4*>(wtp + off) = *reinterpret_cast<const uint4*>(v);
}

// ---------------------------------------------------------------------------
// Main router (round-11 structure + depth-2 gll pipeline, LDS-funded):
//   3 x-buffers; at chunk c issue gll(c+2); end-of-chunk counted vmcnt(4)
//   (= gll(c+2) 2 + nt-stores 2, the only vmem younger than gll(c+1)) +
//   raw s_barrier. Staging for 2 chunks + stores stay in flight -> HBM
//   requests outstanding continuously instead of 10-20% burst duty.
//   B loads in-chunk registers (round-11 proven; NO cross-chunk reg
//   prefetch -- round 12 proved it spills at this budget).
// ---------------------------------------------------------------------------
__global__ __launch_bounds__(512, 2)
void router_mfma(const float* __restrict__ x,
                 const unsigned short* __restrict__ wtp,
                 const float* __restrict__ br,
                 const int*   __restrict__ conn,
                 float* __restrict__ out_x,
                 float* __restrict__ out_p,
                 float* __restrict__ out_n,
                 unsigned* __restrict__ cnt,
                 unsigned* __restrict__ list)
{
    __shared__ float smem[12288];        // xbuf[3][64][64] (48KB) | slog[32][260]

    const int tid  = threadIdx.x;
    const int lane = tid & 63;
    const int wid  = tid >> 6;           // 0..7
    const int wr   = wid >> 2;           // 0..1 (row half)
    const int wc   = wid & 3;            // 0..3 (col quarter)
    const int m16  = lane & 15;
    const int kq   = lane >> 4;          // 0..3
    const long row0 = (long)blockIdx.x * BM;

    f32x4 acc[2][4];
#pragma unroll
    for (int fr = 0; fr < 2; ++fr)
#pragma unroll
        for (int fc = 0; fc < 4; ++fc)
            acc[fr][fc] = (f32x4){0.f, 0.f, 0.f, 0.f};

    // stage chunk c into buf c%3: 2 gll16 per wave (4 rows / 1 KB each)
    auto stage = [&](int c) {
        const int bufW = (c % 3) * 4096;
#pragma unroll
        for (int q = 0; q < 2; ++q) {
            const int rbase = wid * 8 + q * 4;
            const int r     = rbase + (lane >> 4);
            const int u     = (lane & 15) ^ (r & 15);
            gll16(x + (row0 + r) * (long)D_DIM + c * 64 + u * 4,
                  &smem[bufW + rbase * 64]);
        }
    };

    // ---- prologue: chunks 0,1 staged; wait buf0 only (buf1 may fly) ----
    stage(0);
    stage(1);
    asm volatile("s_waitcnt vmcnt(2)" ::: "memory");
    __builtin_amdgcn_s_barrier();

    for (int c = 0; c < NCH; ++c) {
        const int k0   = c * 64;
        const int bufW = (c % 3) * 4096;

        // ---- 1. packed B fragment loads (wave-contiguous 1 KB each) ----
        uint4 bh[4][2], bl[4][2];
        {
            const unsigned short* pc = wtp + (long)c * P_C + (long)wc * 4 * P_FCG
                                       + lane * 8;
#pragma unroll
            for (int fc = 0; fc < 4; ++fc)
#pragma unroll
                for (int ks = 0; ks < 2; ++ks) {
                    const unsigned short* p = pc + fc * P_FCG + ks * P_KS;
                    bh[fc][ks] = *reinterpret_cast<const uint4*>(p);
                    bl[fc][ks] = *reinterpret_cast<const uint4*>(p + P_HL);
                }
        }
        __builtin_amdgcn_sched_barrier(0);

        // ---- 2. gll(c+2) into buf (c+2)%3 (last reader was chunk c-1) ----
        if (c + 2 < NCH) stage(c + 2);
        __builtin_amdgcn_sched_barrier(0);

        // ---- 3. x passthrough: full-line non-temporal stores from LDS ----
        {
            const int row = tid >> 4;        // 0..31
            const int u   = tid & 15;
#pragma unroll
            for (int rg = 0; rg < 2; ++rg) {
                const int r = rg * 32 + row;
                f32x4 v = *reinterpret_cast<const f32x4*>(
                    &smem[bufW + r * 64 + (u ^ (r & 15)) * 4]);
                __builtin_nontemporal_store(v, reinterpret_cast<f32x4*>(
                    out_x + (row0 + r) * (long)D_DIM + k0 + u * 4));
            }
        }
        __builtin_amdgcn_sched_barrier(0);

        // ---- 4. compute: 2 k-steps x 3 passes (hi*hi, lo*hi, hi*lo) ----
#pragma unroll
        for (int ks = 0; ks < 2; ++ks) {
            bf16x8 ah[2], al[2];
#pragma unroll
            for (int fr = 0; fr < 2; ++fr) {
                const int row = wr * 32 + fr * 16 + m16;   // row & 15 == m16
                const int u0  = ks * 8 + kq * 2;
                float4 r0 = *reinterpret_cast<const float4*>(
                    &smem[bufW + row * 64 + ((u0)     ^ m16) * 4]);
                float4 r1 = *reinterpret_cast<const float4*>(
                    &smem[bufW + row * 64 + ((u0 + 1) ^ m16) * 4]);
                split8(r0, r1, ah[fr], al[fr]);
            }
            __builtin_amdgcn_s_setprio(1);
#pragma unroll
            for (int fc = 0; fc < 4; ++fc) {
                const bf16x8 bhv = __builtin_bit_cast(bf16x8, bh[fc][ks]);
                const bf16x8 blv = __builtin_bit_cast(bf16x8, bl[fc][ks]);
#pragma unroll
                for (int fr = 0; fr < 2; ++fr) {
                    acc[fr][fc] = __builtin_amdgcn_mfma_f32_16x16x32_bf16(ah[fr], bhv, acc[fr][fc], 0, 0, 0);
                    acc[fr][fc] = __builtin_amdgcn_mfma_f32_16x16x32_bf16(al[fr], bhv, acc[fr][fc], 0, 0, 0);
                    acc[fr][fc] = __builtin_amdgcn_mfma_f32_16x16x32_bf16(ah[fr], blv, acc[fr][fc], 0, 0, 0);
                }
            }
            __builtin_amdgcn_s_setprio(0);
        }

        // ---- 5. counted barrier: gll(c+1) done; gll(c+2)+stores in flight ----
        if (c + 1 < NCH) {
            __builtin_amdgcn_sched_barrier(0);
            if (c + 2 < NCH) asm volatile("s_waitcnt vmcnt(4)" ::: "memory");
            else             asm volatile("s_waitcnt vmcnt(2)" ::: "memory");
            __builtin_amdgcn_s_barrier();
            __builtin_amdgcn_sched_barrier(0);
        }
    }

    // ---- epilogue: two 32-row halves; register-resident softmax/top-8 ----
#pragma unroll 1
    for (int h = 0; h < 2; ++h) {
        __syncthreads();
        if (wr == h) {
#pragma unroll
            for (int fr = 0; fr < 2; ++fr)
#pragma unroll
                for (int fc = 0; fc < 4; ++fc)
#pragma unroll
                    for (int r = 0; r < 4; ++r) {
                        const int rloc = fr * 16 + kq * 4 + r;     // 0..31
                        const int col  = wc * 64 + fc * 16 + m16;
                        float v = acc[fr][fc][r];
                        v = (col < T_N) ? v + br[col] : -1e30f;
                        smem[rloc * 260 + col] = v;
                    }
        }
        __syncthreads();

        const int rloc = tid >> 4;          // 0..31
        const int sub  = tid & 15;          // 16 threads per row
        const long gr  = row0 + h * 32 + rloc;
        const float* base = &smem[rloc * 260];

        float vals[16];
#pragma unroll
        for (int t = 0; t < 16; ++t) vals[t] = base[sub + 16 * t];

        float m = -INFINITY;
#pragma unroll
        for (int t = 0; t < 16; ++t) m = fmaxf(m, vals[t]);
#pragma unroll
        for (int d = 8; d >= 1; d >>= 1) m = fmaxf(m, __shfl_xor(m, d, 16));

        float e[16]; float s = 0.f;
#pragma unroll
        for (int t = 0; t < 16; ++t) { e[t] = expf(vals[t] - m); s += e[t]; }
#pragma unroll
        for (int d = 8; d >= 1; d >>= 1) s += __shfl_xor(s, d, 16);
        const float inv = 1.0f / s;

        unsigned chosen = 0u;
        float prev = INFINITY;
        int flag = 0;
#pragma unroll 1
        for (int k = 0; k < TOPK + 1; ++k) {
            float bv = -1.f; int bt = 0;
#pragma unroll
            for (int t = 0; t < 16; ++t)
                if (!((chosen >> t) & 1u) && e[t] > bv) { bv = e[t]; bt = t; }
            int bcol = sub + 16 * bt;
#pragma unroll
            for (int d = 8; d >= 1; d >>= 1) {
                const float ov = __shfl_xor(bv, d, 16);
                const int   oc = __shfl_xor(bcol, d, 16);
                if (ov > bv || (ov == bv && oc < bcol)) { bv = ov; bcol = oc; }
            }
            if (bv >= prev * 0.9998f) flag = 1;     // logit gap < 2e-4
            prev = bv;
            if (k < TOPK) {
                if ((bcol & 15) == sub) chosen |= 1u << (bcol >> 4);
                if (sub == 0) {
                    out_p[gr * TOPK + k] = bv * inv;
                    const int* cp = conn + bcol * 3;
                    out_n[(gr * TOPK + k) * 3 + 0] = (float)cp[0];
                    out_n[(gr * TOPK + k) * 3 + 1] = (float)cp[1];
                    out_n[(gr * TOPK + k) * 3 + 2] = (float)cp[2];
                }
            }
        }
        if (sub == 0 && flag) {
            unsigned idx = atomicAdd(cnt, 1u);
            if (idx < 32768u) list[idx] = (unsigned)gr;
        }
    }
}

// ---------------------------------------------------------------------------
// Refine: fp64 recompute for flagged tokens (round-7/8 proven: branchless
// clamped loads, MLP 16, 4 tokens/block, wave-parallel top-8).
// ---------------------------------------------------------------------------
#define RB 4
__global__ __launch_bounds__(512)
void refine_fp64(const float* __restrict__ x,
                 const float* __restrict__ W,
                 const float* __restrict__ br,
                 const int*   __restrict__ conn,
                 float* __restrict__ out_p,
                 float* __restrict__ out_n,
                 const unsigned* __restrict__ cnt,
                 const unsigned* __restrict__ list)
{
    __shared__ float  sx[RB][D_DIM];      // 32 KB
    __shared__ double spart[2][RB][256];  // 16 KB
    __shared__ double slog[RB][256];      // 8 KB

    const int tid  = threadIdx.x;
    const int col  = tid & 255;
    const int kh   = tid >> 8;            // 0..1
    const int colc = (col < T_N) ? col : (T_N - 1);   // branchless clamp
    const int lane = tid & 63;
    const int w    = tid >> 6;            // 0..7
    const unsigned count = min(*cnt, 32768u);

    for (unsigned g0 = (unsigned)blockIdx.x * RB; g0 < count;
         g0 += gridDim.x * RB) {
        const int nb = (int)min((unsigned)RB, count - g0);
        long toks[RB];
#pragma unroll
        for (int j = 0; j < RB; ++j) {
            const unsigned idx = (g0 + j < count) ? (g0 + j) : (count - 1);
            toks[j] = (long)list[idx];
            *reinterpret_cast<float4*>(&sx[j][tid * 4]) =
                *reinterpret_cast<const float4*>(x + toks[j] * D_DIM + tid * 4);
        }
        __syncthreads();

        const int kb = kh * 1024;
        double a0 = 0.0, a1 = 0.0, a2 = 0.0, a3 = 0.0;
        for (int k0 = 0; k0 < 1024; k0 += 16) {
            float wv[16];
#pragma unroll
            for (int i = 0; i < 16; ++i)
                wv[i] = W[(long)(kb + k0 + i) * T_N + colc];  // unconditional
#pragma unroll
            for (int i = 0; i < 16; i += 2) {
                const float2 x0 = *reinterpret_cast<const float2*>(&sx[0][kb + k0 + i]);
                const float2 x1 = *reinterpret_cast<const float2*>(&sx[1][kb + k0 + i]);
                const float2 x2 = *reinterpret_cast<const float2*>(&sx[2][kb + k0 + i]);
                const float2 x3 = *reinterpret_cast<const float2*>(&sx[3][kb + k0 + i]);
                const double w0 = (double)wv[i], w1 = (double)wv[i + 1];
                a0 += (double)x0.x * w0; a0 += (double)x0.y * w1;
                a1 += (double)x1.x * w0; a1 += (double)x1.y * w1;
                a2 += (double)x2.x * w0; a2 += (double)x2.y * w1;
                a3 += (double)x3.x * w0; a3 += (double)x3.y * w1;
            }
        }
        spart[kh][0][col] = a0;
        spart[kh][1][col] = a1;
        spart[kh][2][col] = a2;
        spart[kh][3][col] = a3;
        __syncthreads();

        if (tid < 256) {
#pragma unroll
            for (int j = 0; j < RB; ++j)
                slog[j][tid] = (tid < T_N)
                    ? spart[0][j][tid] + spart[1][j][tid] + (double)br[tid]
                    : -1.0e300;
        }
        __syncthreads();

        if (w < nb) {
            const long tok = toks[w];
            double v[4];
#pragma unroll
            for (int i = 0; i < 4; ++i) v[i] = slog[w][lane + 64 * i];
            double m = fmax(fmax(v[0], v[1]), fmax(v[2], v[3]));
#pragma unroll
            for (int off = 32; off >= 1; off >>= 1)
                m = fmax(m, __shfl_xor(m, off));
            double e[4]; double s = 0.0;
#pragma unroll
            for (int i = 0; i < 4; ++i) {
                e[i] = (v[i] > -1.0e299) ? exp(v[i] - m) : 0.0;
                s += e[i];
            }
#pragma unroll
            for (int off = 32; off >= 1; off >>= 1)
                s += __shfl_xor(s, off);
            const double invZ = 1.0 / s;

            int sel[TOPK];
#pragma unroll 1
            for (int k = 0; k < TOPK; ++k) {
                double bv = -1.0; int bi = 255;
#pragma unroll
                for (int i = 0; i < 4; ++i) {
                    const int t = lane + 64 * i;
                    bool used = false;
                    for (int q = 0; q < k; ++q) used |= (sel[q] == t);
                    if (!used && e[i] > bv) { bv = e[i]; bi = t; }
                }
#pragma unroll
                for (int off = 32; off >= 1; off >>= 1) {
                    const double ov = __shfl_xor(bv, off);
                    const int    oi = __shfl_xor(bi, off);
                    if (ov > bv || (ov == bv && oi < bi)) { bv = ov; bi = oi; }
                }
                sel[k] = bi;
                if (lane == 0) {
                    out_p[tok * TOPK + k] = (float)(bv * invZ);
                    const int* cp = conn + bi * 3;
                    out_n[(tok * TOPK + k) * 3 + 0] = (float)cp[0];
                    out_n[(tok * TOPK + k) * 3 + 1] = (float)cp[1];
                    out_n[(tok * TOPK + k) * 3 + 2] = (float)cp[2];
                }
            }
        }
        __syncthreads();
    }
}

extern "C" void kernel_launch(void* const* d_in, const int* in_sizes, int n_in,
                              void* d_out, int out_size, void* d_ws, size_t ws_size,
                              hipStream_t stream) {
    const float* x    = (const float*)d_in[0];
    const float* Wr   = (const float*)d_in[1];
    const float* br   = (const float*)d_in[2];
    const int*   conn = (const int*)d_in[3];

    float* out_x = (float*)d_out;
    float* out_p = out_x + (size_t)8 * 4096 * 2048;
    float* out_n = out_p + (size_t)8 * 4096 * 8;

    unsigned*       cnt  = (unsigned*)d_ws;
    unsigned*       list = (unsigned*)((char*)d_ws + WS_LIST_OFF);
    unsigned short* wtp  = (unsigned short*)((char*)d_ws + WS_WTP_OFF);

    hipLaunchKernelGGL(prep_pack, dim3(32, 16), dim3(256), 0, stream,
                       Wr, cnt, wtp);
    hipLaunchKernelGGL(router_mfma, dim3(32768 / BM), dim3(512), 0, stream,
                       x, wtp, br, conn, out_x, out_p, out_n, cnt, list);
    hipLaunchKernelGGL(refine_fp64, dim3(512), dim3(512), 0, stream,
                       x, Wr, br, conn, out_p, out_n, cnt, list);
}

// Round 14
// 306.192 us; speedup vs baseline: 2.1646x; 1.0289x over previous
//
#include <hip/hip_runtime.h>
#include <math.h>

#define D_DIM 2048
#define T_N   245
#define TOPK  8
#define BM    64
#define NCH   32              // 2048 / 64

typedef __attribute__((ext_vector_type(8))) __bf16 bf16x8;
typedef __attribute__((ext_vector_type(4))) float  f32x4;

// ws layout (~2.4 MB):
//   [0]        : unsigned counter
//   [256]      : token list, unsigned[32768] (128 KB)
//   [256K]     : wtp packed fragments, bf16 [32][16][2][2][64][8]  (2 MB)
#define WS_LIST_OFF   256
#define WS_WTP_OFF    (256 * 1024)

// packed strides (bf16 units)
#define P_C    32768          // 16*2*2*64*8
#define P_FCG  2048           // 2*2*64*8
#define P_KS   1024           // 2*64*8
#define P_HL   512            // 64*8

__device__ __forceinline__ unsigned short bf16_rne(float f) {
    unsigned u = __builtin_bit_cast(unsigned, f);
    u += 0x7FFFu + ((u >> 16) & 1u);
    return (unsigned short)(u >> 16);
}
__device__ __forceinline__ float bf16_to_f(unsigned short h) {
    return __builtin_bit_cast(float, (unsigned)h << 16);
}

// async global->LDS, 16 B per lane: one instr stages 4 rows (1 KB)
__device__ __forceinline__ void gll16(const float* g, float* l) {
    __builtin_amdgcn_global_load_lds(
        (const __attribute__((address_space(1))) void*)g,
        (__attribute__((address_space(3))) void*)l, 16, 0, 0);
}

// split 8 f32 -> hi/lo bf16x8 using v_cvt_pk_bf16_f32 (RNE)
__device__ __forceinline__ void split8(const float4& A, const float4& B,
                                       bf16x8& h8, bf16x8& l8) {
    const float f[8] = {A.x, A.y, A.z, A.w, B.x, B.y, B.z, B.w};
    unsigned hu[4], lu[4];
#pragma unroll
    for (int p = 0; p < 4; ++p) {
        unsigned uh;
        asm("v_cvt_pk_bf16_f32 %0, %1, %2" : "=v"(uh) : "v"(f[2*p]), "v"(f[2*p+1]));
        const float h0 = __builtin_bit_cast(float, uh << 16);
        const float h1 = __builtin_bit_cast(float, uh & 0xffff0000u);
        const float l0 = f[2*p] - h0;
        const float l1 = f[2*p+1] - h1;
        unsigned ul;
        asm("v_cvt_pk_bf16_f32 %0, %1, %2" : "=v"(ul) : "v"(l0), "v"(l1));
        hu[p] = uh; lu[p] = ul;
    }
    uint4 vh = make_uint4(hu[0], hu[1], hu[2], hu[3]);
    uint4 vl = make_uint4(lu[0], lu[1], lu[2], lu[3]);
    h8 = __builtin_bit_cast(bf16x8, vh);
    l8 = __builtin_bit_cast(bf16x8, vl);
}

// ---------------------------------------------------------------------------
// Prep: W [2048][245] fp32 -> wtp packed fragment-major bf16 hi/lo.
// ---------------------------------------------------------------------------
__global__ __launch_bounds__(256)
void prep_pack(const float* __restrict__ W,
               unsigned* __restrict__ cnt,
               unsigned short* __restrict__ wtp)
{
    if (blockIdx.x == 0 && blockIdx.y == 0 && threadIdx.x == 0) *cnt = 0u;

    const int c   = blockIdx.x;          // 0..31
    const int fcg = blockIdx.y;          // 0..15
    const int tid = threadIdx.x;
    const int ks   = tid >> 7;           // 0..1
    const int hl   = (tid >> 6) & 1;     // 0..1
    const int lane = tid & 63;

    const int row = fcg * 16 + (lane & 15);
    const int kb  = c * 64 + ks * 32 + (lane >> 4) * 8;

    unsigned short v[8];
#pragma unroll
    for (int j = 0; j < 8; ++j) {
        const float f = (row < T_N) ? W[(long)(kb + j) * T_N + row] : 0.0f;
        const unsigned short h = bf16_rne(f);
        v[j] = hl ? bf16_rne(f - bf16_to_f(h)) : h;
    }
    const long off = (long)c * P_C + (long)fcg * P_FCG + ks * P_KS
                     + hl * P_HL + lane * 8;
    *reinterpret_cast<uint4*>(wtp + off) = *reinterpret_cast<const uint4*>(v);
}

// ---------------------------------------------------------------------------
// Main router (round-13 structure + B loads spanning the barrier):
//   B(c+1) loaded into the SAME bh/bl registers at the END of chunk c
//   (after last MFMA use -> zero extra registers), then counted
//   vmcnt(20) (= gll(c+2) 2 + st 2 + B(c+1) 16 newest; in-order VMEM
//   retirement drains gll(c+1)) + raw s_barrier. B latency is covered by
//   the barrier + next chunk's gll/stores/split8 instead of fully exposed.
// ---------------------------------------------------------------------------
__global__ __launch_bounds__(512, 2)
void router_mfma(const float* __restrict__ x,
                 const unsigned short* __restrict__ wtp,
                 const float* __restrict__ br,
                 const int*   __restrict__ conn,
                 float* __restrict__ out_x,
                 float* __restrict__ out_p,
                 float* __restrict__ out_n,
                 unsigned* __restrict__ cnt,
                 unsigned* __restrict__ list)
{
    __shared__ float smem[12288];        // xbuf[3][64][64] (48KB) | slog[32][260]

    const int tid  = threadIdx.x;
    const int lane = tid & 63;
    const int wid  = tid >> 6;           // 0..7
    const int wr   = wid >> 2;           // 0..1 (row half)
    const int wc   = wid & 3;            // 0..3 (col quarter)
    const int m16  = lane & 15;
    const int kq   = lane >> 4;          // 0..3
    const long row0 = (long)blockIdx.x * BM;

    f32x4 acc[2][4];
#pragma unroll
    for (int fr = 0; fr < 2; ++fr)
#pragma unroll
        for (int fc = 0; fc < 4; ++fc)
            acc[fr][fc] = (f32x4){0.f, 0.f, 0.f, 0.f};

    // stage chunk c into buf c%3: 2 gll16 per wave (4 rows / 1 KB each)
    auto stage = [&](int c) {
        const int bufW = (c % 3) * 4096;
#pragma unroll
        for (int q = 0; q < 2; ++q) {
            const int rbase = wid * 8 + q * 4;
            const int r     = rbase + (lane >> 4);
            const int u     = (lane & 15) ^ (r & 15);
            gll16(x + (row0 + r) * (long)D_DIM + c * 64 + u * 4,
                  &smem[bufW + rbase * 64]);
        }
    };

    // B fragments for chunk c -> bh/bl (register rotation, no double-buffer)
    uint4 bh[4][2], bl[4][2];
    auto loadB = [&](int c) {
        const unsigned short* pc = wtp + (long)c * P_C + (long)wc * 4 * P_FCG
                                   + lane * 8;
#pragma unroll
        for (int fc = 0; fc < 4; ++fc)
#pragma unroll
            for (int ks = 0; ks < 2; ++ks) {
                const unsigned short* p = pc + fc * P_FCG + ks * P_KS;
                bh[fc][ks] = *reinterpret_cast<const uint4*>(p);
                bl[fc][ks] = *reinterpret_cast<const uint4*>(p + P_HL);
            }
    };

    // ---- prologue: stage 0,1 + B(0); drain glls only (B(0) may fly) ----
    stage(0);
    stage(1);
    loadB(0);
    __builtin_amdgcn_sched_barrier(0);
    asm volatile("s_waitcnt vmcnt(16)" ::: "memory");
    __builtin_amdgcn_s_barrier();

    for (int c = 0; c < NCH; ++c) {
        const int k0   = c * 64;
        const int bufW = (c % 3) * 4096;

        // ---- 1. gll(c+2) into buf (c+2)%3 (last reader was chunk c-1) ----
        if (c + 2 < NCH) stage(c + 2);
        __builtin_amdgcn_sched_barrier(0);

        // ---- 2. x passthrough: full-line non-temporal stores from LDS ----
        {
            const int row = tid >> 4;        // 0..31
            const int u   = tid & 15;
#pragma unroll
            for (int rg = 0; rg < 2; ++rg) {
                const int r = rg * 32 + row;
                f32x4 v = *reinterpret_cast<const f32x4*>(
                    &smem[bufW + r * 64 + (u ^ (r & 15)) * 4]);
                __builtin_nontemporal_store(v, reinterpret_cast<f32x4*>(
                    out_x + (row0 + r) * (long)D_DIM + k0 + u * 4));
            }
        }
        __builtin_amdgcn_sched_barrier(0);

        // ---- 3. compute: 2 k-steps x 3 passes (hi*hi, lo*hi, hi*lo) ----
#pragma unroll
        for (int ks = 0; ks < 2; ++ks) {
            bf16x8 ah[2], al[2];
#pragma unroll
            for (int fr = 0; fr < 2; ++fr) {
                const int row = wr * 32 + fr * 16 + m16;   // row & 15 == m16
                const int u0  = ks * 8 + kq * 2;
                float4 r0 = *reinterpret_cast<const float4*>(
                    &smem[bufW + row * 64 + ((u0)     ^ m16) * 4]);
                float4 r1 = *reinterpret_cast<const float4*>(
                    &smem[bufW + row * 64 + ((u0 + 1) ^ m16) * 4]);
                split8(r0, r1, ah[fr], al[fr]);
            }
            __builtin_amdgcn_s_setprio(1);
#pragma unroll
            for (int fc = 0; fc < 4; ++fc) {
                const bf16x8 bhv = __builtin_bit_cast(bf16x8, bh[fc][ks]);
                const bf16x8 blv = __builtin_bit_cast(bf16x8, bl[fc][ks]);
#pragma unroll
                for (int fr = 0; fr < 2; ++fr) {
                    acc[fr][fc] = __builtin_amdgcn_mfma_f32_16x16x32_bf16(ah[fr], bhv, acc[fr][fc], 0, 0, 0);
                    acc[fr][fc] = __builtin_amdgcn_mfma_f32_16x16x32_bf16(al[fr], bhv, acc[fr][fc], 0, 0, 0);
                    acc[fr][fc] = __builtin_amdgcn_mfma_f32_16x16x32_bf16(ah[fr], blv, acc[fr][fc], 0, 0, 0);
                }
            }
            __builtin_amdgcn_s_setprio(0);
        }

        // ---- 4. B(c+1) into the now-dead bh/bl, then counted barrier ----
        if (c + 1 < NCH) {
            __builtin_amdgcn_sched_barrier(0);
            loadB(c + 1);
            __builtin_amdgcn_sched_barrier(0);
            // outstanding (newest): B(c+1) 16 + st(c) 2 [+ gll(c+2) 2]
            if (c + 2 < NCH) asm volatile("s_waitcnt vmcnt(20)" ::: "memory");
            else             asm volatile("s_waitcnt vmcnt(18)" ::: "memory");
            __builtin_amdgcn_s_barrier();
            __builtin_amdgcn_sched_barrier(0);
        }
    }

    // ---- epilogue: two 32-row halves; register-resident softmax/top-8 ----
#pragma unroll 1
    for (int h = 0; h < 2; ++h) {
        __syncthreads();
        if (wr == h) {
#pragma unroll
            for (int fr = 0; fr < 2; ++fr)
#pragma unroll
                for (int fc = 0; fc < 4; ++fc)
#pragma unroll
                    for (int r = 0; r < 4; ++r) {
                        const int rloc = fr * 16 + kq * 4 + r;     // 0..31
                        const int col  = wc * 64 + fc * 16 + m16;
                        float v = acc[fr][fc][r];
                        v = (col < T_N) ? v + br[col] : -1e30f;
                        smem[rloc * 260 + col] = v;
                    }
        }
        __syncthreads();

        const int rloc = tid >> 4;          // 0..31
        const int sub  = tid & 15;          // 16 threads per row
        const long gr  = row0 + h * 32 + rloc;
        const float* base = &smem[rloc * 260];

        float vals[16];
#pragma unroll
        for (int t = 0; t < 16; ++t) vals[t] = base[sub + 16 * t];

        float m = -INFINITY;
#pragma unroll
        for (int t = 0; t < 16; ++t) m = fmaxf(m, vals[t]);
#pragma unroll
        for (int d = 8; d >= 1; d >>= 1) m = fmaxf(m, __shfl_xor(m, d, 16));

        float e[16]; float s = 0.f;
#pragma unroll
        for (int t = 0; t < 16; ++t) { e[t] = expf(vals[t] - m); s += e[t]; }
#pragma unroll
        for (int d = 8; d >= 1; d >>= 1) s += __shfl_xor(s, d, 16);
        const float inv = 1.0f / s;

        unsigned chosen = 0u;
        float prev = INFINITY;
        int flag = 0;
#pragma unroll 1
        for (int k = 0; k < TOPK + 1; ++k) {
            float bv = -1.f; int bt = 0;
#pragma unroll
            for (int t = 0; t < 16; ++t)
                if (!((chosen >> t) & 1u) && e[t] > bv) { bv = e[t]; bt = t; }
            int bcol = sub + 16 * bt;
#pragma unroll
            for (int d = 8; d >= 1; d >>= 1) {
                const float ov = __shfl_xor(bv, d, 16);
                const int   oc = __shfl_xor(bcol, d, 16);
                if (ov > bv || (ov == bv && oc < bcol)) { bv = ov; bcol = oc; }
            }
            if (bv >= prev * 0.9998f) flag = 1;     // logit gap < 2e-4
            prev = bv;
            if (k < TOPK) {
                if ((bcol & 15) == sub) chosen |= 1u << (bcol >> 4);
                if (sub == 0) {
                    out_p[gr * TOPK + k] = bv * inv;
                    const int* cp = conn + bcol * 3;
                    out_n[(gr * TOPK + k) * 3 + 0] = (float)cp[0];
                    out_n[(gr * TOPK + k) * 3 + 1] = (float)cp[1];
                    out_n[(gr * TOPK + k) * 3 + 2] = (float)cp[2];
                }
            }
        }
        if (sub == 0 && flag) {
            unsigned idx = atomicAdd(cnt, 1u);
            if (idx < 32768u) list[idx] = (unsigned)gr;
        }
    }
}

// ---------------------------------------------------------------------------
// Refine: fp64 recompute for flagged tokens (round-7/8 proven: branchless
// clamped loads, MLP 16, 4 tokens/block, wave-parallel top-8).
// ---------------------------------------------------------------------------
#define RB 4
__global__ __launch_bounds__(512)
void refine_fp64(const float* __restrict__ x,
                 const float* __restrict__ W,
                 const float* __restrict__ br,
                 const int*   __restrict__ conn,
                 float* __restrict__ out_p,
                 float* __restrict__ out_n,
                 const unsigned* __restrict__ cnt,
                 const unsigned* __restrict__ list)
{
    __shared__ float  sx[RB][D_DIM];      // 32 KB
    __shared__ double spart[2][RB][256];  // 16 KB
    __shared__ double slog[RB][256];      // 8 KB

    const int tid  = threadIdx.x;
    const int col  = tid & 255;
    const int kh   = tid >> 8;            // 0..1
    const int colc = (col < T_N) ? col : (T_N - 1);   // branchless clamp
    const int lane = tid & 63;
    const int w    = tid >> 6;            // 0..7
    const unsigned count = min(*cnt, 32768u);

    for (unsigned g0 = (unsigned)blockIdx.x * RB; g0 < count;
         g0 += gridDim.x * RB) {
        const int nb = (int)min((unsigned)RB, count - g0);
        long toks[RB];
#pragma unroll
        for (int j = 0; j < RB; ++j) {
            const unsigned idx = (g0 + j < count) ? (g0 + j) : (count - 1);
            toks[j] = (long)list[idx];
            *reinterpret_cast<float4*>(&sx[j][tid * 4]) =
                *reinterpret_cast<const float4*>(x + toks[j] * D_DIM + tid * 4);
        }
        __syncthreads();

        const int kb = kh * 1024;
        double a0 = 0.0, a1 = 0.0, a2 = 0.0, a3 = 0.0;
        for (int k0 = 0; k0 < 1024; k0 += 16) {
            float wv[16];
#pragma unroll
            for (int i = 0; i < 16; ++i)
                wv[i] = W[(long)(kb + k0 + i) * T_N + colc];  // unconditional
#pragma unroll
            for (int i = 0; i < 16; i += 2) {
                const float2 x0 = *reinterpret_cast<const float2*>(&sx[0][kb + k0 + i]);
                const float2 x1 = *reinterpret_cast<const float2*>(&sx[1][kb + k0 + i]);
                const float2 x2 = *reinterpret_cast<const float2*>(&sx[2][kb + k0 + i]);
                const float2 x3 = *reinterpret_cast<const float2*>(&sx[3][kb + k0 + i]);
                const double w0 = (double)wv[i], w1 = (double)wv[i + 1];
                a0 += (double)x0.x * w0; a0 += (double)x0.y * w1;
                a1 += (double)x1.x * w0; a1 += (double)x1.y * w1;
                a2 += (double)x2.x * w0; a2 += (double)x2.y * w1;
                a3 += (double)x3.x * w0; a3 += (double)x3.y * w1;
            }
        }
        spart[kh][0][col] = a0;
        spart[kh][1][col] = a1;
        spart[kh][2][col] = a2;
        spart[kh][3][col] = a3;
        __syncthreads();

        if (tid < 256) {
#pragma unroll
            for (int j = 0; j < RB; ++j)
                slog[j][tid] = (tid < T_N)
                    ? spart[0][j][tid] + spart[1][j][tid] + (double)br[tid]
                    : -1.0e300;
        }
        __syncthreads();

        if (w < nb) {
            const long tok = toks[w];
            double v[4];
#pragma unroll
            for (int i = 0; i < 4; ++i) v[i] = slog[w][lane + 64 * i];
            double m = fmax(fmax(v[0], v[1]), fmax(v[2], v[3]));
#pragma unroll
            for (int off = 32; off >= 1; off >>= 1)
                m = fmax(m, __shfl_xor(m, off));
            double e[4]; double s = 0.0;
#pragma unroll
            for (int i = 0; i < 4; ++i) {
                e[i] = (v[i] > -1.0e299) ? exp(v[i] - m) : 0.0;
                s += e[i];
            }
#pragma unroll
            for (int off = 32; off >= 1; off >>= 1)
                s += __shfl_xor(s, off);
            const double invZ = 1.0 / s;

            int sel[TOPK];
#pragma unroll 1
            for (int k = 0; k < TOPK; ++k) {
                double bv = -1.0; int bi = 255;
#pragma unroll
                for (int i = 0; i < 4; ++i) {
                    const int t = lane + 64 * i;
                    bool used = false;
                    for (int q = 0; q < k; ++q) used |= (sel[q] == t);
                    if (!used && e[i] > bv) { bv = e[i]; bi = t; }
                }
#pragma unroll
                for (int off = 32; off >= 1; off >>= 1) {
                    const double ov = __shfl_xor(bv, off);
                    const int    oi = __shfl_xor(bi, off);
                    if (ov > bv || (ov == bv && oi < bi)) { bv = ov; bi = oi; }
                }
                sel[k] = bi;
                if (lane == 0) {
                    out_p[tok * TOPK + k] = (float)(bv * invZ);
                    const int* cp = conn + bi * 3;
                    out_n[(tok * TOPK + k) * 3 + 0] = (float)cp[0];
                    out_n[(tok * TOPK + k) * 3 + 1] = (float)cp[1];
                    out_n[(tok * TOPK + k) * 3 + 2] = (float)cp[2];
                }
            }
        }
        __syncthreads();
    }
}

extern "C" void kernel_launch(void* const* d_in, const int* in_sizes, int n_in,
                              void* d_out, int out_size, void* d_ws, size_t ws_size,
                              hipStream_t stream) {
    const float* x    = (const float*)d_in[0];
    const float* Wr   = (const float*)d_in[1];
    const float* br   = (const float*)d_in[2];
    const int*   conn = (const int*)d_in[3];

    float* out_x = (float*)d_out;
    float* out_p = out_x + (size_t)8 * 4096 * 2048;
    float* out_n = out_p + (size_t)8 * 4096 * 8;

    unsigned*       cnt  = (unsigned*)d_ws;
    unsigned*       list = (unsigned*)((char*)d_ws + WS_LIST_OFF);
    unsigned short* wtp  = (unsigned short*)((char*)d_ws + WS_WTP_OFF);

    hipLaunchKernelGGL(prep_pack, dim3(32, 16), dim3(256), 0, stream,
                       Wr, cnt, wtp);
    hipLaunchKernelGGL(router_mfma, dim3(32768 / BM), dim3(512), 0, stream,
                       x, wtp, br, conn, out_x, out_p, out_n, cnt, list);
    hipLaunchKernelGGL(refine_fp64, dim3(512), dim3(512), 0, stream,
                       x, Wr, br, conn, out_p, out_n, cnt, list);
}